// Round 1
// baseline (194.666 us; speedup 1.0000x reference)
//
#include <hip/hip_runtime.h>

// out[b,c] = sum_{h,w} coeff[h,w] * x[b,c,h,w] + bias
// coeff[h,w] = (1/25) * sum over 5x5/s2 windows (oh,ow) covering (h,w) of W[oh*6+ow]
//
// One 64-lane wave per channel: lane i loads float4 at x[ch*256 + i*4],
// dots with its 4 coeffs (computed once per wave), shfl-reduces, lane 0 writes.

#define CH_TOTAL (256 * 512)   // B*C
#define BLOCK 256

__global__ __launch_bounds__(BLOCK) void pool_linear_kernel(
    const float* __restrict__ x,
    const float* __restrict__ Wv,
    const float* __restrict__ bv,
    float* __restrict__ out)
{
    const int lane   = threadIdx.x & 63;
    const int waveId = (int)((blockIdx.x * blockDim.x + threadIdx.x) >> 6);
    const int nWaves = (int)((gridDim.x * blockDim.x) >> 6);

    // Per-lane coefficients for pixel positions p = lane*4 + j  (h = p/16, w = p%16).
    // Window oh covers rows [2*oh, 2*oh+4]; valid oh range = [ceil((h-4)/2), floor(h/2)] ∩ [0,5].
    float c[4];
#pragma unroll
    for (int j = 0; j < 4; ++j) {
        const int p = lane * 4 + j;
        const int h = p >> 4;
        const int w = p & 15;
        const int oh0 = max(0, (h - 3) / 2);   // ceil((h-4)/2) clamped at 0
        const int oh1 = min(5, h >> 1);
        const int ow0 = max(0, (w - 3) / 2);
        const int ow1 = min(5, w >> 1);
        float s = 0.0f;
        for (int oh = oh0; oh <= oh1; ++oh)
            for (int ow = ow0; ow <= ow1; ++ow)
                s += Wv[oh * 6 + ow];
        c[j] = s * 0.04f;                      // 1/25
    }
    const float bias = bv[0];

    const float4* __restrict__ x4 = reinterpret_cast<const float4*>(x);

    for (int ch = waveId; ch < CH_TOTAL; ch += nWaves) {
        const float4 v = x4[ch * 64 + lane];   // coalesced: 64 lanes x 16B = 1KB channel
        float part = v.x * c[0] + v.y * c[1] + v.z * c[2] + v.w * c[3];
#pragma unroll
        for (int off = 32; off > 0; off >>= 1)
            part += __shfl_down(part, off, 64);
        if (lane == 0) out[ch] = part + bias;
    }
}

extern "C" void kernel_launch(void* const* d_in, const int* in_sizes, int n_in,
                              void* d_out, int out_size, void* d_ws, size_t ws_size,
                              hipStream_t stream) {
    const float* x   = (const float*)d_in[0];
    const float* Wv  = (const float*)d_in[1];
    const float* bv  = (const float*)d_in[2];
    float* out       = (float*)d_out;

    // 2048 blocks x 4 waves = 8192 waves; 131072 channels -> 16 channels/wave.
    pool_linear_kernel<<<dim3(2048), dim3(BLOCK), 0, stream>>>(x, Wv, bv, out);
}